// Round 13
// baseline (149.999 us; speedup 1.0000x reference)
//
#include <hip/hip_runtime.h>

#define DIMC 1024
#define HEADS 16
#define HD 64
#define BATCH 2
#define SEQ 1024
#define NQKV 3072

typedef _Float16 f16;
typedef _Float16 half8 __attribute__((ext_vector_type(8)));
typedef _Float16 half4v __attribute__((ext_vector_type(4)));
typedef float floatx4 __attribute__((ext_vector_type(4)));

__device__ __forceinline__ void gld16(const void* g, void* l) {
  __builtin_amdgcn_global_load_lds((const __attribute__((address_space(1))) void*)g,
                                   (__attribute__((address_space(3))) void*)l, 16, 0, 0);
}

__device__ __forceinline__ unsigned sadU8(unsigned a, unsigned b, unsigned c) {
#if __has_builtin(__builtin_amdgcn_sad_u8)
  return __builtin_amdgcn_sad_u8(a, b, c);
#else
  unsigned d;
  asm("v_sad_u8 %0, %1, %2, %3" : "=v"(d) : "v"(a), "v"(b), "v"(c));
  return d;
#endif
}

// ---------------- f32 -> f16 casts (x, qkv_w, proj_w), 4 float4/thread ----------------
__global__ __launch_bounds__(256) void cvt_kernel(
    const float* __restrict__ x, const float* __restrict__ wq, const float* __restrict__ wp,
    f16* __restrict__ x16, f16* __restrict__ wq16, f16* __restrict__ wp16)
{
  int bid = blockIdx.x;
  const float* src; f16* dst; int base;
  if (bid < 512)        { src = x;  dst = x16;  base = bid; }
  else if (bid < 1280)  { src = wq; dst = wq16; base = bid - 512; }
  else                  { src = wp; dst = wp16; base = bid - 1280; }
  long long i0 = (long long)base*1024 + threadIdx.x;
#pragma unroll
  for (int k2 = 0; k2 < 4; ++k2) {
    long long i = i0 + k2*256;   // float4 index, coalesced
    float4 v = ((const float4*)src)[i];
    half4v h; h[0]=(f16)v.x; h[1]=(f16)v.y; h[2]=(f16)v.z; h[3]=(f16)v.w;
    *(half4v*)(dst + i*4) = h;
  }
}

// ---------------- TM x TN f16 MFMA GEMM, 2-phase double-buffered staging ----------
// MODE 0: QKV -> q8/k8 (u8 quant, [b,h,s,d]) and vT (f16, [b,h,d,s])
// MODE 1: proj -> f32 out [t, f]
// R24 (resubmitted unchanged after R12 infra failure — container acquisition
// died twice, same as R5 which cleared on resubmit; source audit found no
// fault: LDS 64KB/64KB at MW=2, linear gld16 dests, correct dbuf handoff).
// T3 minimum 2-phase pipeline: all prior gemm rounds (tile/BK/MW/grid —
// neutral) kept the serial barrier->stage->drain->compute skeleton. Fix =
// double-buffer As/Bs, ISSUE next tile's gld16 BEFORE computing current, one
// barrier/kt: drain becomes max(0, latency - Tcompute). Same mechanism R19
// proved in attn's k8s dbuf.
template<int TM, int TN, int BK, int MW, int MODE>
__global__ __launch_bounds__(256, MW) void gemm_kernel(
    const f16* __restrict__ A, const f16* __restrict__ Bw, const float* __restrict__ bias,
    unsigned char* __restrict__ q8, unsigned char* __restrict__ k8, f16* __restrict__ vT,
    float* __restrict__ outp, int K)
{
  constexpr int MT = TM / 32;   // m-subtiles per wave
  constexpr int NT = TN / 32;   // n-subtiles per wave
  constexpr int G  = BK / 8;    // 16B groups per LDS row
  __shared__ f16 As[2][TM*BK];
  __shared__ f16 Bs[2][TN*BK];
  const int tid = threadIdx.x;
  const int wave = tid >> 6, lane = tid & 63;
  const int lq = lane >> 4, li = lane & 15;
  const int m0 = blockIdx.y * TM, n0 = blockIdx.x * TN;
  const int wm = (wave & 1) * (TM/2), wn = (wave >> 1) * (TN/2);
  floatx4 acc[MT][NT] = {};

  const int kIters = K / BK;

#define GEMM_STAGE(buf, kt)                                                     \
  {                                                                             \
    _Pragma("unroll")                                                           \
    for (int r = 0; r < TM*BK/2048; ++r) {                                      \
      int slot = r*256 + tid;                                                   \
      int row = slot / G, c = slot % G, g = c ^ (row & (G-1));                  \
      gld16(A + (size_t)(m0+row)*K + (kt)*BK + g*8, As[buf] + slot*8);          \
    }                                                                           \
    _Pragma("unroll")                                                           \
    for (int r = 0; r < TN*BK/2048; ++r) {                                      \
      int slot = r*256 + tid;                                                   \
      int row = slot / G, c = slot % G, g = c ^ (row & (G-1));                  \
      gld16(Bw + (size_t)(n0+row)*K + (kt)*BK + g*8, Bs[buf] + slot*8);         \
    }                                                                           \
  }

  GEMM_STAGE(0, 0);
  __syncthreads();                       // buf0 landed (vmcnt drain in barrier)

  for (int kt = 0; kt < kIters; ++kt) {
    const int cur = kt & 1;
    if (kt + 1 < kIters) GEMM_STAGE(cur ^ 1, kt + 1);   // issue early
#pragma unroll
    for (int ks = 0; ks < BK/32; ++ks) {
      half8 af[MT], bf[NT];
      int kc = ks*4 + lq;
#pragma unroll
      for (int t = 0; t < MT; ++t) {
        int am = wm + t*16 + li;
        af[t] = *(const half8*)&As[cur][am*BK + (kc ^ (am & (G-1)))*8];
      }
#pragma unroll
      for (int t = 0; t < NT; ++t) {
        int bn = wn + t*16 + li;
        bf[t] = *(const half8*)&Bs[cur][bn*BK + (kc ^ (bn & (G-1)))*8];
      }
#pragma unroll
      for (int mt = 0; mt < MT; ++mt)
#pragma unroll
        for (int nt = 0; nt < NT; ++nt)
          acc[mt][nt] = __builtin_amdgcn_mfma_f32_16x16x32_f16(af[mt], bf[nt], acc[mt][nt], 0, 0, 0);
    }
    __syncthreads();   // next buf landed; all waves done reading cur
  }
#undef GEMM_STAGE

#pragma unroll
  for (int mt = 0; mt < MT; ++mt) {
#pragma unroll
    for (int nt = 0; nt < NT; ++nt) {
      int f = n0 + wn + nt*16 + li;                 // output feature (col, from B)
      float bb = bias[f];
      if (MODE == 0) {
        int which = f >> 10, cc = f & 1023, h = cc >> 6, d = cc & 63;
        int t0 = m0 + wm + mt*16 + lq*4;            // token (row, from A), 4 consecutive
        int b = t0 >> 10, s0 = t0 & 1023;
        if (which == 2) {
          half4v hv;
#pragma unroll
          for (int r = 0; r < 4; ++r) hv[r] = (f16)(acc[mt][nt][r] + bb);
          *(half4v*)&vT[((size_t)((b*HEADS + h)*HD + d))*SEQ + s0] = hv;
        } else {
          unsigned char* dst = (which == 0) ? q8 : k8;
#pragma unroll
          for (int r = 0; r < 4; ++r) {
            float v = acc[mt][nt][r] + bb;
            int u = (int)floorf(v * 16.0f + 128.5f);
            u = u < 0 ? 0 : (u > 255 ? 255 : u);
            dst[((size_t)((b*HEADS + h)*SEQ + s0 + r))*HD + d] = (unsigned char)u;
          }
        }
      } else {
#pragma unroll
        for (int r = 0; r < 4; ++r) {
          int t = m0 + wm + mt*16 + lq*4 + r;
          outp[(size_t)t*DIMC + f] = acc[mt][nt][r] + bb;
        }
      }
    }
  }
}

// ---------------- Laplacian attention + depthwise conv, y16 out ----------------
// Exact R19 (proven best: attn 44.1-44.5us). Eight structural variants
// (R15-R22) all landed 44.5-48.6 -> plateau; frozen.
__global__ __launch_bounds__(256, 3) void attn_kernel(
    const unsigned char* __restrict__ q8g, const unsigned char* __restrict__ k8g,
    const f16* __restrict__ vTg, const float* __restrict__ dwcw, const float* __restrict__ dwcb,
    f16* __restrict__ y16)
{
  __shared__ unsigned char q8s[32*64];     //  2KB
  __shared__ unsigned char k8s[2][128*64]; // 16KB double-buffered, chunk-swizzled
  __shared__ f16 sfrag[2][8*64*8];         // 16KB double-buffered A-frag scores
  __shared__ float rspart[32*16];          //  2KB
  __shared__ float rowsum[32];             // total ~36.4KB

  const int tid = threadIdx.x;
  const int lin = blockIdx.x + 16 * blockIdx.y;      // 0..1023
  const int bh = (lin & 7) * 4 + ((lin >> 3) & 3);   // XCD-grouped head index
  const int i0 = (lin >> 5) * 32;                    // 32 i-blocks of 32 rows
  const int lane = tid & 63, wave = tid >> 6;
  const int lq = lane >> 4, li = lane & 15;
  const int iL = tid & 15, jt = tid >> 4;       // phase-1 mapping
  const int ksj = jt >> 2, qj = jt & 3;
  const int scs = jt & 3;                       // chunk-swizzle read key

  { // stage q tile (32x64B, waves 0-1) + k8s[0] with chunk swizzle
    if (tid < 128)
      gld16(q8g + ((size_t)(bh*SEQ) + i0)*HD + tid*16, q8s + tid*16);
#pragma unroll
    for (int r = 0; r < 2; ++r) {
      int slot = r*256 + tid;
      int row = slot >> 2, c4 = slot & 3, sc4 = c4 ^ ((row >> 3) & 3);
      gld16(k8g + ((size_t)(bh*SEQ) + row)*HD + sc4*16, k8s[0] + slot*16);
    }
  }
  __syncthreads();

  // q rows {iL, iL+16} into regs (32 u32 — the size that provably stays resident)
  unsigned qr[2][16];
#pragma unroll
  for (int n = 0; n < 2; ++n)
#pragma unroll
    for (int c4 = 0; c4 < 4; ++c4) {
      uint4 t = *(const uint4*)&q8s[(iL + n*16)*64 + c4*16];
      qr[n][c4*4+0] = t.x; qr[n][c4*4+1] = t.y; qr[n][c4*4+2] = t.z; qr[n][c4*4+3] = t.w;
    }

  float rs[2] = {0.f, 0.f};
  floatx4 pacc[2] = {};                  // this wave owns d-strip wave*16..+15
  const f16* vbase = vTg + ((size_t)(bh*HD) + wave*16 + li)*SEQ;

  for (int jb = 0; jb < 8; ++jb) {
    const int j0 = jb * 128;
    const int cur = jb & 1;

    // stage NEXT k tile (consumed in iter jb+1; lands by this iter's barrier)
    if (jb < 7) {
#pragma unroll
      for (int r = 0; r < 2; ++r) {
        int slot = r*256 + tid;
        int row = slot >> 2, c4 = slot & 3, sc4 = c4 ^ ((row >> 3) & 3);
        gld16(k8g + ((size_t)(bh*SEQ) + j0 + 128 + row)*HD + sc4*16,
              k8s[cur ^ 1] + slot*16);
      }
    }
    // issue this iter's V B-frags (global->reg, waited at MFMA use)
    half8 vfrag[4];
#pragma unroll
    for (int ks = 0; ks < 4; ++ks)
      vfrag[ks] = *(const half8*)(vbase + j0 + (ks*4 + lq)*8);

    // ---- phase 1: SAD distances from k8s[cur] (staged last iter) ----
    unsigned sacc[2][8] = {};
#pragma unroll
    for (int c4 = 0; c4 < 4; ++c4) {
      uint4 kk[8];
#pragma unroll
      for (int jj = 0; jj < 8; ++jj)
        kk[jj] = *(const uint4*)&k8s[cur][(jt*8 + jj)*64 + ((c4 ^ scs) << 4)];
#pragma unroll
      for (int n = 0; n < 2; ++n)
#pragma unroll
        for (int jj = 0; jj < 8; ++jj) {
          sacc[n][jj] = sadU8(qr[n][c4*4+0], kk[jj].x, sacc[n][jj]);
          sacc[n][jj] = sadU8(qr[n][c4*4+1], kk[jj].y, sacc[n][jj]);
          sacc[n][jj] = sadU8(qr[n][c4*4+2], kk[jj].z, sacc[n][jj]);
          sacc[n][jj] = sadU8(qr[n][c4*4+3], kk[jj].w, sacc[n][jj]);
        }
    }
    // kern = exp(-dist/16), dist = sad/16  ->  exp2(-sad * log2(e)/256)
#pragma unroll
    for (int n = 0; n < 2; ++n) {
      half8 sv;
#pragma unroll
      for (int jj = 0; jj < 8; ++jj) {
        float sf = exp2f(-0.0056355275f * (float)sacc[n][jj]);
        rs[n] += sf;
        sv[jj] = (f16)sf;
      }
      *(half8*)&sfrag[cur][((n*4 + ksj)*64 + qj*16 + iL)*8] = sv;
    }
    __syncthreads();   // sfrag[cur] ready; k8s[cur^1] landed (vmcnt drain)

    // ---- phase 2: PV via MFMA, wave tile 32i x 16d, B from regs ----
#pragma unroll
    for (int ks = 0; ks < 4; ++ks) {
      half8 a0 = *(const half8*)&sfrag[cur][((0*4 + ks)*64 + lane)*8];
      half8 a1 = *(const half8*)&sfrag[cur][((1*4 + ks)*64 + lane)*8];
      pacc[0] = __builtin_amdgcn_mfma_f32_16x16x32_f16(a0, vfrag[ks], pacc[0], 0, 0, 0);
      pacc[1] = __builtin_amdgcn_mfma_f32_16x16x32_f16(a1, vfrag[ks], pacc[1], 0, 0, 0);
    }
  }

  // rowsum reduction across the 16 j-slices
#pragma unroll
  for (int n = 0; n < 2; ++n) rspart[(iL + n*16)*16 + jt] = rs[n];
  __syncthreads();
  if (tid < 32) {
    float s = 0.f;
#pragma unroll
    for (int t = 0; t < 16; ++t) s += rspart[tid*16 + t];
    rowsum[tid] = s + 1e-6f;
  }
  __syncthreads();

  // epilogue: normalize + depthwise conv + store y16 [b,s,h*64+d]
  const int b = bh >> 4, h = bh & 15;
  {
    int d = wave*16 + li;
    int c = h*64 + d;
    float w0 = dwcw[c*3+0], w1 = dwcw[c*3+1], w2 = dwcw[c*3+2], cb = dwcb[c];
    const f16* vrow = vTg + ((size_t)(bh*HD) + d)*SEQ;
#pragma unroll
    for (int mt = 0; mt < 2; ++mt) {
      int s0 = i0 + mt*16 + lq*4;                  // first of 4 consecutive rows
      float vv[6];
#pragma unroll
      for (int e = 0; e < 6; ++e) {
        int s = s0 - 1 + e;
        vv[e] = (s >= 0 && s < SEQ) ? (float)vrow[s] : 0.f;
      }
#pragma unroll
      for (int r = 0; r < 4; ++r) {
        int ii = mt*16 + lq*4 + r;
        float val = pacc[mt][r] / rowsum[ii];
        val += w0*vv[r] + w1*vv[r+1] + w2*vv[r+2] + cb;
        int s = i0 + ii;
        y16[((size_t)(b*SEQ + s))*DIMC + c] = (f16)val;
      }
    }
  }
}

extern "C" void kernel_launch(void* const* d_in, const int* in_sizes, int n_in,
                              void* d_out, int out_size, void* d_ws, size_t ws_size,
                              hipStream_t stream) {
  const float* x      = (const float*)d_in[0];
  const float* qkv_w  = (const float*)d_in[1];
  const float* qkv_b  = (const float*)d_in[2];
  const float* proj_w = (const float*)d_in[3];
  const float* proj_b = (const float*)d_in[4];
  const float* dwc_w  = (const float*)d_in[5];
  const float* dwc_b  = (const float*)d_in[6];
  float* out = (float*)d_out;

  char* ws = (char*)d_ws;
  f16* x16  = (f16*)(ws);                         //  4 MB
  f16* wq16 = (f16*)(ws + (4ll<<20));             //  6 MB
  f16* wp16 = (f16*)(ws + (10ll<<20));            //  2 MB
  unsigned char* q8 = (unsigned char*)(ws + (12ll<<20));  // 2 MB
  unsigned char* k8 = (unsigned char*)(ws + (14ll<<20));  // 2 MB
  f16* vT   = (f16*)(ws + (16ll<<20));            //  4 MB
  f16* y16  = (f16*)(ws + (20ll<<20));            //  4 MB (total 24 MB)

  cvt_kernel<<<1536, 256, 0, stream>>>(x, qkv_w, proj_w, x16, wq16, wp16);
  // gemm0: 128x128 tile, BK=64, 2-phase dbuf (64KB LDS) — grid 24x16 = 384
  gemm_kernel<128,128,64,2,0><<<dim3(24, 16), 256, 0, stream>>>(x16, wq16, qkv_b, q8, k8, vT, nullptr, DIMC);
  // attn: 1024 blocks (32 bh x 32 i-blocks of 32 rows)
  attn_kernel<<<dim3(16, 64), 256, 0, stream>>>(q8, k8, vT, dwc_w, dwc_b, y16);
  // gemm1: 64x64 tile, BK=128, 2-phase dbuf (64KB LDS) — grid 16x32 = 512
  gemm_kernel<64,64,128,2,1><<<dim3(16, 32), 256, 0, stream>>>(y16, wp16, proj_b, nullptr, nullptr, nullptr, out, DIMC);
}

// Round 14
// 147.908 us; speedup vs baseline: 1.0141x; 1.0141x over previous
//
#include <hip/hip_runtime.h>

#define DIMC 1024
#define HEADS 16
#define HD 64
#define BATCH 2
#define SEQ 1024
#define NQKV 3072

typedef _Float16 f16;
typedef _Float16 half8 __attribute__((ext_vector_type(8)));
typedef _Float16 half4v __attribute__((ext_vector_type(4)));
typedef float floatx4 __attribute__((ext_vector_type(4)));

__device__ __forceinline__ void gld16(const void* g, void* l) {
  __builtin_amdgcn_global_load_lds((const __attribute__((address_space(1))) void*)g,
                                   (__attribute__((address_space(3))) void*)l, 16, 0, 0);
}

__device__ __forceinline__ unsigned sadU8(unsigned a, unsigned b, unsigned c) {
#if __has_builtin(__builtin_amdgcn_sad_u8)
  return __builtin_amdgcn_sad_u8(a, b, c);
#else
  unsigned d;
  asm("v_sad_u8 %0, %1, %2, %3" : "=v"(d) : "v"(a), "v"(b), "v"(c));
  return d;
#endif
}

// ---------------- f32 -> f16 casts (x, qkv_w, proj_w), 4 float4/thread ----------------
__global__ __launch_bounds__(256) void cvt_kernel(
    const float* __restrict__ x, const float* __restrict__ wq, const float* __restrict__ wp,
    f16* __restrict__ x16, f16* __restrict__ wq16, f16* __restrict__ wp16)
{
  int bid = blockIdx.x;
  const float* src; f16* dst; int base;
  if (bid < 512)        { src = x;  dst = x16;  base = bid; }
  else if (bid < 1280)  { src = wq; dst = wq16; base = bid - 512; }
  else                  { src = wp; dst = wp16; base = bid - 1280; }
  long long i0 = (long long)base*1024 + threadIdx.x;
#pragma unroll
  for (int k2 = 0; k2 < 4; ++k2) {
    long long i = i0 + k2*256;   // float4 index, coalesced
    float4 v = ((const float4*)src)[i];
    half4v h; h[0]=(f16)v.x; h[1]=(f16)v.y; h[2]=(f16)v.z; h[3]=(f16)v.w;
    *(half4v*)(dst + i*4) = h;
  }
}

// ---------------- TM x TN f16 MFMA GEMM (BK-deep K-tiles), C = A * Bw^T + bias ----
// MODE 0: QKV -> q8/k8 (u8 quant, [b,h,s,d]) and vT (f16, [b,h,d,s])
// MODE 1: proj -> f32 out [t, f]
// R25: FINAL revert to the proven serial template. Six gemm config families
// (tile/BK/MW/grid/residency R14,R17,R23 + 2-phase dbuf R24) all neutral-to-
// negative within +-3us -> this is the m97-structure's shape-limited floor
// (m102 curve: ~320 TF at N~2048-class; the 8-phase 256^2 escape needs
// hundreds of tiles, our N=3072/1024 gives only 96/32 blocks on 256 CUs).
template<int TM, int TN, int BK, int MW, int MODE>
__global__ __launch_bounds__(256, MW) void gemm_kernel(
    const f16* __restrict__ A, const f16* __restrict__ Bw, const float* __restrict__ bias,
    unsigned char* __restrict__ q8, unsigned char* __restrict__ k8, f16* __restrict__ vT,
    float* __restrict__ outp, int K)
{
  constexpr int MT = TM / 32;   // m-subtiles per wave
  constexpr int NT = TN / 32;   // n-subtiles per wave
  constexpr int G  = BK / 8;    // 16B groups per LDS row
  __shared__ f16 As[TM*BK];
  __shared__ f16 Bs[TN*BK];
  const int tid = threadIdx.x;
  const int wave = tid >> 6, lane = tid & 63;
  const int lq = lane >> 4, li = lane & 15;
  const int m0 = blockIdx.y * TM, n0 = blockIdx.x * TN;
  const int wm = (wave & 1) * (TM/2), wn = (wave >> 1) * (TN/2);
  floatx4 acc[MT][NT] = {};

  const int kIters = K / BK;
  for (int kt = 0; kt < kIters; ++kt) {
    __syncthreads();
#pragma unroll
    for (int r = 0; r < TM*BK/2048; ++r) {
      int slot = r*256 + tid;
      int row = slot / G, c = slot % G, g = c ^ (row & (G-1));
      gld16(A + (size_t)(m0+row)*K + kt*BK + g*8, As + slot*8);
    }
#pragma unroll
    for (int r = 0; r < TN*BK/2048; ++r) {
      int slot = r*256 + tid;
      int row = slot / G, c = slot % G, g = c ^ (row & (G-1));
      gld16(Bw + (size_t)(n0+row)*K + kt*BK + g*8, Bs + slot*8);
    }
    __syncthreads();
#pragma unroll
    for (int ks = 0; ks < BK/32; ++ks) {
      half8 af[MT], bf[NT];
      int kc = ks*4 + lq;
#pragma unroll
      for (int t = 0; t < MT; ++t) {
        int am = wm + t*16 + li;
        af[t] = *(const half8*)&As[am*BK + (kc ^ (am & (G-1)))*8];
      }
#pragma unroll
      for (int t = 0; t < NT; ++t) {
        int bn = wn + t*16 + li;
        bf[t] = *(const half8*)&Bs[bn*BK + (kc ^ (bn & (G-1)))*8];
      }
#pragma unroll
      for (int mt = 0; mt < MT; ++mt)
#pragma unroll
        for (int nt = 0; nt < NT; ++nt)
          acc[mt][nt] = __builtin_amdgcn_mfma_f32_16x16x32_f16(af[mt], bf[nt], acc[mt][nt], 0, 0, 0);
    }
  }

#pragma unroll
  for (int mt = 0; mt < MT; ++mt) {
#pragma unroll
    for (int nt = 0; nt < NT; ++nt) {
      int f = n0 + wn + nt*16 + li;                 // output feature (col, from B)
      float bb = bias[f];
      if (MODE == 0) {
        int which = f >> 10, cc = f & 1023, h = cc >> 6, d = cc & 63;
        int t0 = m0 + wm + mt*16 + lq*4;            // token (row, from A), 4 consecutive
        int b = t0 >> 10, s0 = t0 & 1023;
        if (which == 2) {
          half4v hv;
#pragma unroll
          for (int r = 0; r < 4; ++r) hv[r] = (f16)(acc[mt][nt][r] + bb);
          *(half4v*)&vT[((size_t)((b*HEADS + h)*HD + d))*SEQ + s0] = hv;
        } else {
          unsigned char* dst = (which == 0) ? q8 : k8;
#pragma unroll
          for (int r = 0; r < 4; ++r) {
            float v = acc[mt][nt][r] + bb;
            int u = (int)floorf(v * 16.0f + 128.5f);
            u = u < 0 ? 0 : (u > 255 ? 255 : u);
            dst[((size_t)((b*HEADS + h)*SEQ + s0 + r))*HD + d] = (unsigned char)u;
          }
        }
      } else {
#pragma unroll
        for (int r = 0; r < 4; ++r) {
          int t = m0 + wm + mt*16 + lq*4 + r;
          outp[(size_t)t*DIMC + f] = acc[mt][nt][r] + bb;
        }
      }
    }
  }
}

// ---------------- Laplacian attention + depthwise conv, y16 out ----------------
// Exact R19 (best measured: attn 44.1-44.5us, total 146.47 in R7's run).
// Eight structural variants (R15-R22) all landed 44.5-48.6 -> plateau.
// Structure: 1024 blocks (32 bh x 32 i-blocks of 32 q-rows), chunk-swizzled
// double-buffered k8s (1 barrier/jb), vfrag direct from L2, SAD in u8 via
// v_sad_u8, PV via 16x16x32 f16 MFMA with sfrag A-frag relay.
__global__ __launch_bounds__(256, 3) void attn_kernel(
    const unsigned char* __restrict__ q8g, const unsigned char* __restrict__ k8g,
    const f16* __restrict__ vTg, const float* __restrict__ dwcw, const float* __restrict__ dwcb,
    f16* __restrict__ y16)
{
  __shared__ unsigned char q8s[32*64];     //  2KB
  __shared__ unsigned char k8s[2][128*64]; // 16KB double-buffered, chunk-swizzled
  __shared__ f16 sfrag[2][8*64*8];         // 16KB double-buffered A-frag scores
  __shared__ float rspart[32*16];          //  2KB
  __shared__ float rowsum[32];             // total ~36.4KB

  const int tid = threadIdx.x;
  const int lin = blockIdx.x + 16 * blockIdx.y;      // 0..1023
  const int bh = (lin & 7) * 4 + ((lin >> 3) & 3);   // XCD-grouped head index
  const int i0 = (lin >> 5) * 32;                    // 32 i-blocks of 32 rows
  const int lane = tid & 63, wave = tid >> 6;
  const int lq = lane >> 4, li = lane & 15;
  const int iL = tid & 15, jt = tid >> 4;       // phase-1 mapping
  const int ksj = jt >> 2, qj = jt & 3;
  const int scs = jt & 3;                       // chunk-swizzle read key

  { // stage q tile (32x64B, waves 0-1) + k8s[0] with chunk swizzle
    if (tid < 128)
      gld16(q8g + ((size_t)(bh*SEQ) + i0)*HD + tid*16, q8s + tid*16);
#pragma unroll
    for (int r = 0; r < 2; ++r) {
      int slot = r*256 + tid;
      int row = slot >> 2, c4 = slot & 3, sc4 = c4 ^ ((row >> 3) & 3);
      gld16(k8g + ((size_t)(bh*SEQ) + row)*HD + sc4*16, k8s[0] + slot*16);
    }
  }
  __syncthreads();

  // q rows {iL, iL+16} into regs (32 u32 — the size that provably stays resident)
  unsigned qr[2][16];
#pragma unroll
  for (int n = 0; n < 2; ++n)
#pragma unroll
    for (int c4 = 0; c4 < 4; ++c4) {
      uint4 t = *(const uint4*)&q8s[(iL + n*16)*64 + c4*16];
      qr[n][c4*4+0] = t.x; qr[n][c4*4+1] = t.y; qr[n][c4*4+2] = t.z; qr[n][c4*4+3] = t.w;
    }

  float rs[2] = {0.f, 0.f};
  floatx4 pacc[2] = {};                  // this wave owns d-strip wave*16..+15
  const f16* vbase = vTg + ((size_t)(bh*HD) + wave*16 + li)*SEQ;

  for (int jb = 0; jb < 8; ++jb) {
    const int j0 = jb * 128;
    const int cur = jb & 1;

    // stage NEXT k tile (consumed in iter jb+1; lands by this iter's barrier)
    if (jb < 7) {
#pragma unroll
      for (int r = 0; r < 2; ++r) {
        int slot = r*256 + tid;
        int row = slot >> 2, c4 = slot & 3, sc4 = c4 ^ ((row >> 3) & 3);
        gld16(k8g + ((size_t)(bh*SEQ) + j0 + 128 + row)*HD + sc4*16,
              k8s[cur ^ 1] + slot*16);
      }
    }
    // issue this iter's V B-frags (global->reg, waited at MFMA use)
    half8 vfrag[4];
#pragma unroll
    for (int ks = 0; ks < 4; ++ks)
      vfrag[ks] = *(const half8*)(vbase + j0 + (ks*4 + lq)*8);

    // ---- phase 1: SAD distances from k8s[cur] (staged last iter) ----
    unsigned sacc[2][8] = {};
#pragma unroll
    for (int c4 = 0; c4 < 4; ++c4) {
      uint4 kk[8];
#pragma unroll
      for (int jj = 0; jj < 8; ++jj)
        kk[jj] = *(const uint4*)&k8s[cur][(jt*8 + jj)*64 + ((c4 ^ scs) << 4)];
#pragma unroll
      for (int n = 0; n < 2; ++n)
#pragma unroll
        for (int jj = 0; jj < 8; ++jj) {
          sacc[n][jj] = sadU8(qr[n][c4*4+0], kk[jj].x, sacc[n][jj]);
          sacc[n][jj] = sadU8(qr[n][c4*4+1], kk[jj].y, sacc[n][jj]);
          sacc[n][jj] = sadU8(qr[n][c4*4+2], kk[jj].z, sacc[n][jj]);
          sacc[n][jj] = sadU8(qr[n][c4*4+3], kk[jj].w, sacc[n][jj]);
        }
    }
    // kern = exp(-dist/16), dist = sad/16  ->  exp2(-sad * log2(e)/256)
#pragma unroll
    for (int n = 0; n < 2; ++n) {
      half8 sv;
#pragma unroll
      for (int jj = 0; jj < 8; ++jj) {
        float sf = exp2f(-0.0056355275f * (float)sacc[n][jj]);
        rs[n] += sf;
        sv[jj] = (f16)sf;
      }
      *(half8*)&sfrag[cur][((n*4 + ksj)*64 + qj*16 + iL)*8] = sv;
    }
    __syncthreads();   // sfrag[cur] ready; k8s[cur^1] landed (vmcnt drain)

    // ---- phase 2: PV via MFMA, wave tile 32i x 16d, B from regs ----
#pragma unroll
    for (int ks = 0; ks < 4; ++ks) {
      half8 a0 = *(const half8*)&sfrag[cur][((0*4 + ks)*64 + lane)*8];
      half8 a1 = *(const half8*)&sfrag[cur][((1*4 + ks)*64 + lane)*8];
      pacc[0] = __builtin_amdgcn_mfma_f32_16x16x32_f16(a0, vfrag[ks], pacc[0], 0, 0, 0);
      pacc[1] = __builtin_amdgcn_mfma_f32_16x16x32_f16(a1, vfrag[ks], pacc[1], 0, 0, 0);
    }
  }

  // rowsum reduction across the 16 j-slices
#pragma unroll
  for (int n = 0; n < 2; ++n) rspart[(iL + n*16)*16 + jt] = rs[n];
  __syncthreads();
  if (tid < 32) {
    float s = 0.f;
#pragma unroll
    for (int t = 0; t < 16; ++t) s += rspart[tid*16 + t];
    rowsum[tid] = s + 1e-6f;
  }
  __syncthreads();

  // epilogue: normalize + depthwise conv + store y16 [b,s,h*64+d]
  const int b = bh >> 4, h = bh & 15;
  {
    int d = wave*16 + li;
    int c = h*64 + d;
    float w0 = dwcw[c*3+0], w1 = dwcw[c*3+1], w2 = dwcw[c*3+2], cb = dwcb[c];
    const f16* vrow = vTg + ((size_t)(bh*HD) + d)*SEQ;
#pragma unroll
    for (int mt = 0; mt < 2; ++mt) {
      int s0 = i0 + mt*16 + lq*4;                  // first of 4 consecutive rows
      float vv[6];
#pragma unroll
      for (int e = 0; e < 6; ++e) {
        int s = s0 - 1 + e;
        vv[e] = (s >= 0 && s < SEQ) ? (float)vrow[s] : 0.f;
      }
#pragma unroll
      for (int r = 0; r < 4; ++r) {
        int ii = mt*16 + lq*4 + r;
        float val = pacc[mt][r] / rowsum[ii];
        val += w0*vv[r] + w1*vv[r+1] + w2*vv[r+2] + cb;
        int s = i0 + ii;
        y16[((size_t)(b*SEQ + s))*DIMC + c] = (f16)val;
      }
    }
  }
}

extern "C" void kernel_launch(void* const* d_in, const int* in_sizes, int n_in,
                              void* d_out, int out_size, void* d_ws, size_t ws_size,
                              hipStream_t stream) {
  const float* x      = (const float*)d_in[0];
  const float* qkv_w  = (const float*)d_in[1];
  const float* qkv_b  = (const float*)d_in[2];
  const float* proj_w = (const float*)d_in[3];
  const float* proj_b = (const float*)d_in[4];
  const float* dwc_w  = (const float*)d_in[5];
  const float* dwc_b  = (const float*)d_in[6];
  float* out = (float*)d_out;

  char* ws = (char*)d_ws;
  f16* x16  = (f16*)(ws);                         //  4 MB
  f16* wq16 = (f16*)(ws + (4ll<<20));             //  6 MB
  f16* wp16 = (f16*)(ws + (10ll<<20));            //  2 MB
  unsigned char* q8 = (unsigned char*)(ws + (12ll<<20));  // 2 MB
  unsigned char* k8 = (unsigned char*)(ws + (14ll<<20));  // 2 MB
  f16* vT   = (f16*)(ws + (16ll<<20));            //  4 MB
  f16* y16  = (f16*)(ws + (20ll<<20));            //  4 MB (total 24 MB)

  cvt_kernel<<<1536, 256, 0, stream>>>(x, qkv_w, proj_w, x16, wq16, wp16);
  // gemm0: 128x128 tile, BK=128 (8 K-iters) — grid 24x16 = 384 blocks (proven)
  gemm_kernel<128,128,128,2,0><<<dim3(24, 16), 256, 0, stream>>>(x16, wq16, qkv_b, q8, k8, vT, nullptr, DIMC);
  // attn: 1024 blocks (32 bh x 32 i-blocks of 32 rows)
  attn_kernel<<<dim3(16, 64), 256, 0, stream>>>(q8, k8, vT, dwc_w, dwc_b, y16);
  // gemm1: 64x64 tile, BK=128 — grid 16x32 = 512 blocks (proven)
  gemm_kernel<64,64,128,4,1><<<dim3(16, 32), 256, 0, stream>>>(y16, wp16, proj_b, nullptr, nullptr, nullptr, out, DIMC);
}